// Round 3
// baseline (1042.237 us; speedup 1.0000x reference)
//
#include <hip/hip_runtime.h>
#include <math.h>

#define F_IN 512
#define H1 16
#define C_OUT 7
// bucket = dst >> 8 (256 nodes per bucket); pack = (dst&255)<<17 | src (n < 2^17)

__global__ void k_zero(int* __restrict__ p, int n) {
    int i = blockIdx.x * 256 + threadIdx.x;
    if (i < n) p[i] = 0;
}

__global__ void k_hist(const int* __restrict__ dst, int* __restrict__ indeg, int E) {
    int e = blockIdx.x * 256 + threadIdx.x;
    if (e < E) atomicAdd(&indeg[dst[e]], 1);
}

__global__ void k_dinv(const int* __restrict__ indeg, float* __restrict__ dinv, int n) {
    int i = blockIdx.x * 256 + threadIdx.x;
    if (i < n) dinv[i] = rsqrtf(1.0f + (float)indeg[i]);
}

// ---------- bucket fill pass 1: per-block bucket histogram (coalesced writes) ----------
__global__ __launch_bounds__(1024) void k_fill_p1(const int* __restrict__ dst,
                                                  int* __restrict__ cnt, int E, int B) {
    __shared__ int lh[512];               // B <= 512
    int t = threadIdx.x;
    for (int i = t; i < B; i += 1024) lh[i] = 0;
    __syncthreads();
    int e0 = blockIdx.x * 4096;
#pragma unroll
    for (int k = 0; k < 4; k++) {
        int e = e0 + t + 1024 * k;
        if (e < E) atomicAdd(&lh[dst[e] >> 8], 1);
    }
    __syncthreads();
    for (int i = t; i < B; i += 1024) cnt[(size_t)blockIdx.x * B + i] = lh[i];
}

// ---------- per-bucket exclusive scan over blocks (no contention) ----------
__global__ __launch_bounds__(256) void k_colscan(const int* __restrict__ cnt,
                                                 int* __restrict__ base,
                                                 int* __restrict__ btotal, int nfb, int B) {
    int b = blockIdx.x;
    int t = threadIdx.x;
    int loc[4];
    int s = 0;
    int j0 = t * 4;                        // nfb <= 1024
#pragma unroll
    for (int k = 0; k < 4; k++) {
        int j = j0 + k;
        int v = (j < nfb) ? cnt[(size_t)j * B + b] : 0;
        loc[k] = s;
        s += v;
    }
    __shared__ int sh[256];
    sh[t] = s;
    __syncthreads();
    for (int off = 1; off < 256; off <<= 1) {
        int v2 = (t >= off) ? sh[t - off] : 0;
        __syncthreads();
        sh[t] += v2;
        __syncthreads();
    }
    int excl = sh[t] - s;
#pragma unroll
    for (int k = 0; k < 4; k++) {
        int j = j0 + k;
        if (j < nfb) base[(size_t)j * B + b] = excl + loc[k];
    }
    if (t == 255) btotal[b] = sh[255];
}

// ---------- exclusive scan of bucket totals ----------
__global__ __launch_bounds__(512) void k_sscan(const int* __restrict__ btotal,
                                               int* __restrict__ bstart, int B) {
    __shared__ int s[512];
    int t = threadIdx.x;
    int v = (t < B) ? btotal[t] : 0;
    s[t] = v;
    __syncthreads();
    for (int off = 1; off < 512; off <<= 1) {
        int x = (t >= off) ? s[t - off] : 0;
        __syncthreads();
        s[t] += x;
        __syncthreads();
    }
    if (t < B) bstart[t] = s[t] - v;
}

// ---------- bucket fill pass 2: LDS bucket-sort + run-coalesced writes ----------
__global__ __launch_bounds__(1024) void k_fill_p2(
    const int* __restrict__ src, const int* __restrict__ dst,
    const int* __restrict__ base, const int* __restrict__ bstart,
    unsigned* __restrict__ bedge, int E, int B) {
    __shared__ int lh[512];
    __shared__ int scan[512];             // becomes exclusive local base
    __shared__ int gb[512];
    __shared__ unsigned lsort[4096];
    __shared__ unsigned short lbk[4096];
    int t = threadIdx.x;
    for (int i = t; i < B; i += 1024) lh[i] = 0;
    __syncthreads();
    int e0 = blockIdx.x * 4096;
    int myb[4], myr[4];
    unsigned myv[4];
#pragma unroll
    for (int k = 0; k < 4; k++) {
        int e = e0 + t + 1024 * k;
        myb[k] = -1;
        if (e < E) {
            int d = dst[e];
            int b = d >> 8;
            myb[k] = b;
            myv[k] = ((unsigned)(d & 255) << 17) | (unsigned)src[e];
            myr[k] = atomicAdd(&lh[b], 1);     // LDS ds_add_rtn: fast
        }
    }
    __syncthreads();
    int v = 0;
    if (t < 512) {
        v = (t < B) ? lh[t] : 0;
        scan[t] = v;
    }
    __syncthreads();
    for (int off = 1; off < 512; off <<= 1) {
        int x = 0;
        if (t < 512 && t >= off) x = scan[t - off];
        __syncthreads();
        if (t < 512) scan[t] += x;
        __syncthreads();
    }
    if (t < 512) scan[t] -= v;            // exclusive local base
    __syncthreads();
    if (t < B) gb[t] = bstart[t] + base[(size_t)blockIdx.x * B + t];
    __syncthreads();
#pragma unroll
    for (int k = 0; k < 4; k++) {
        if (myb[k] >= 0) {
            int slot = scan[myb[k]] + myr[k];
            lsort[slot] = myv[k];
            lbk[slot] = (unsigned short)myb[k];
        }
    }
    __syncthreads();
    int elim = min(4096, E - e0);
    for (int i = t; i < elim; i += 1024) {
        int b = lbk[i];
        bedge[gb[b] + (i - scan[b])] = lsort[i];   // coalesced within runs
    }
}

// ---------- GEMM1: g1 = dinv * (x @ W1) ----------
__global__ __launch_bounds__(256) void k_gemm1(
    const float* __restrict__ x, const float* __restrict__ W1,
    const float* __restrict__ dinv, float* __restrict__ g1, int n) {
    __shared__ float xs[32 * 257];
    const int tid = threadIdx.x;
    const int rowbase = blockIdx.x * 256;
    const int row = rowbase + tid;

    float acc[H1];
#pragma unroll
    for (int c = 0; c < H1; c++) acc[c] = 0.0f;

    for (int kc = 0; kc < F_IN; kc += 32) {
        __syncthreads();
#pragma unroll
        for (int j = 0; j < 8; j++) {
            int flat = tid + 256 * j;
            int r = flat >> 3;
            int kq = flat & 7;
            int grow = rowbase + r;
            float4 v = make_float4(0.f, 0.f, 0.f, 0.f);
            if (grow < n) v = *(const float4*)(x + (size_t)grow * F_IN + kc + kq * 4);
            xs[(kq * 4 + 0) * 257 + r] = v.x;
            xs[(kq * 4 + 1) * 257 + r] = v.y;
            xs[(kq * 4 + 2) * 257 + r] = v.z;
            xs[(kq * 4 + 3) * 257 + r] = v.w;
        }
        __syncthreads();
#pragma unroll 4
        for (int k = 0; k < 32; k++) {
            float xv = xs[k * 257 + tid];
            const float* w = W1 + (kc + k) * H1;
#pragma unroll
            for (int c = 0; c < H1; c++) acc[c] = fmaf(xv, w[c], acc[c]);
        }
    }

    if (row < n) {
        float d = dinv[row];
#pragma unroll
        for (int c = 0; c < H1; c++) g1[(size_t)row * H1 + c] = acc[c] * d;
    }
}

// ---------- aggregation layer 1: LDS accumulator per bucket, fused ReLU ----------
__global__ __launch_bounds__(1024) void k_agg1(
    const unsigned* __restrict__ bedge, const int* __restrict__ bstart,
    const int* __restrict__ btotal, const float* __restrict__ g1,
    const float* __restrict__ dinv, const float* __restrict__ b1,
    float* __restrict__ r1, int n) {
    __shared__ float acc[256 * 17];       // pad 17: conflict-free rows
    int t = threadIdx.x;
    int bb = blockIdx.x;
    for (int i = t; i < 256 * 17; i += 1024) acc[i] = 0.f;
    __syncthreads();
    int gs = bstart[bb];
    int ge = gs + btotal[bb];
    int slot = t >> 4, c = t & 15;
    for (int e = gs + slot; e < ge; e += 64) {
        unsigned v = bedge[e];
        int s = v & 131071;
        int dl = v >> 17;
        atomicAdd(&acc[dl * 17 + c], g1[(size_t)s * H1 + c]);   // LDS float atomic
    }
    __syncthreads();
    int nodebase = bb << 8;
    for (int i = t; i < 256 * 16; i += 1024) {
        int dl = i >> 4, cc = i & 15;
        int node = nodebase + dl;
        if (node < n) {
            float sum = acc[dl * 17 + cc] + g1[(size_t)node * H1 + cc];  // + self-loop
            float val = fmaf(dinv[node], sum, b1[cc]);
            r1[(size_t)node * H1 + cc] = fmaxf(val, 0.f);
        }
    }
}

// ---------- GEMM2: g2 = dinv * (r1 @ W2), row stride 8, col 7 = 0 ----------
__global__ __launch_bounds__(256) void k_gemm2(
    const float* __restrict__ r1, const float* __restrict__ W2,
    const float* __restrict__ dinv, float* __restrict__ g2, int n) {
    __shared__ float xs[16 * 257];
    const int tid = threadIdx.x;
    const int rowbase = blockIdx.x * 256;
    const int row = rowbase + tid;

#pragma unroll
    for (int j = 0; j < 4; j++) {
        int flat = tid + 256 * j;
        int r = flat >> 2;
        int kq = flat & 3;
        int grow = rowbase + r;
        float4 v = make_float4(0.f, 0.f, 0.f, 0.f);
        if (grow < n) v = *(const float4*)(r1 + (size_t)grow * H1 + kq * 4);
        xs[(kq * 4 + 0) * 257 + r] = v.x;
        xs[(kq * 4 + 1) * 257 + r] = v.y;
        xs[(kq * 4 + 2) * 257 + r] = v.z;
        xs[(kq * 4 + 3) * 257 + r] = v.w;
    }
    __syncthreads();

    float acc[C_OUT];
#pragma unroll
    for (int c = 0; c < C_OUT; c++) acc[c] = 0.0f;
#pragma unroll
    for (int k = 0; k < H1; k++) {
        float xv = xs[k * 257 + tid];
        const float* w = W2 + k * C_OUT;
#pragma unroll
        for (int c = 0; c < C_OUT; c++) acc[c] = fmaf(xv, w[c], acc[c]);
    }

    if (row < n) {
        float d = dinv[row];
#pragma unroll
        for (int c = 0; c < C_OUT; c++) g2[(size_t)row * 8 + c] = acc[c] * d;
        g2[(size_t)row * 8 + 7] = 0.0f;
    }
}

// ---------- aggregation layer 2 + fused log_softmax ----------
__global__ __launch_bounds__(1024) void k_agg2(
    const unsigned* __restrict__ bedge, const int* __restrict__ bstart,
    const int* __restrict__ btotal, const float* __restrict__ g2,
    const float* __restrict__ dinv, const float* __restrict__ b2,
    float* __restrict__ out, int n) {
    __shared__ float acc[256 * 9];        // pad 9: rotate banks
    int t = threadIdx.x;
    int bb = blockIdx.x;
    for (int i = t; i < 256 * 9; i += 1024) acc[i] = 0.f;
    __syncthreads();
    int gs = bstart[bb];
    int ge = gs + btotal[bb];
    int slot = t >> 3, c = t & 7;
    for (int e = gs + slot; e < ge; e += 128) {
        unsigned v = bedge[e];
        int s = v & 131071;
        int dl = v >> 17;
        atomicAdd(&acc[dl * 9 + c], g2[(size_t)s * 8 + c]);
    }
    __syncthreads();
    int nodebase = bb << 8;
#pragma unroll
    for (int r = 0; r < 2; r++) {
        int dl = (t >> 3) + r * 128;
        int node = nodebase + dl;
        float val = 0.f;
        if (node < n) {
            float sum = acc[dl * 9 + c] + g2[(size_t)node * 8 + c];   // + self-loop
            float bc = (c < C_OUT) ? b2[c] : 0.f;
            val = fmaf(dinv[node], sum, bc);
        }
        float vv = (c < C_OUT) ? val : -1e30f;
        float m = vv;
#pragma unroll
        for (int o = 1; o < 8; o <<= 1) m = fmaxf(m, __shfl_xor(m, o, 8));
        float ex = (c < C_OUT) ? expf(val - m) : 0.f;
        float se = ex;
#pragma unroll
        for (int o = 1; o < 8; o <<= 1) se += __shfl_xor(se, o, 8);
        float l = logf(se) + m;
        if (node < n && c < C_OUT) out[(size_t)node * C_OUT + c] = val - l;
    }
}

extern "C" void kernel_launch(void* const* d_in, const int* in_sizes, int n_in,
                              void* d_out, int out_size, void* d_ws, size_t ws_size,
                              hipStream_t stream) {
    const float* x  = (const float*)d_in[0];
    const int* ei   = (const int*)d_in[1];
    const float* W1 = (const float*)d_in[2];
    const float* b1 = (const float*)d_in[3];
    const float* W2 = (const float*)d_in[4];
    const float* b2 = (const float*)d_in[5];
    float* out = (float*)d_out;

    const int n = in_sizes[0] / F_IN;     // 100000
    const int E = in_sizes[1] / 2;        // 3200000
    const int* src = ei;
    const int* dst = ei + E;

    const int B   = (n + 255) >> 8;       // 391 buckets (<=512)
    const int nfb = (E + 4095) >> 12;     // 782 fill blocks (<=1024)

    // workspace (4-byte units)
    int*   indeg  = (int*)d_ws;                            // n
    float* dinv   = (float*)(indeg + n);                   // n
    float* g1     = dinv + n;                              // 16n (g2 aliases low 8n)
    float* r1     = g1 + (size_t)16 * n;                   // 16n
    int*   cnt    = (int*)(r1 + (size_t)16 * n);           // nfb*B
    int*   base   = cnt + (size_t)nfb * B;                 // nfb*B
    int*   btotal = base + (size_t)nfb * B;                // B
    int*   bstart = btotal + B;                            // B
    unsigned* bedge = (unsigned*)(bstart + B);             // E
    float* g2 = g1;

    const int nbN = (n + 255) / 256;
    const int nbE = (E + 255) / 256;

    k_zero<<<nbN, 256, 0, stream>>>(indeg, n);
    k_hist<<<nbE, 256, 0, stream>>>(dst, indeg, E);
    k_dinv<<<nbN, 256, 0, stream>>>(indeg, dinv, n);

    k_fill_p1<<<nfb, 1024, 0, stream>>>(dst, cnt, E, B);
    k_colscan<<<B, 256, 0, stream>>>(cnt, base, btotal, nfb, B);
    k_sscan<<<1, 512, 0, stream>>>(btotal, bstart, B);
    k_fill_p2<<<nfb, 1024, 0, stream>>>(src, dst, base, bstart, bedge, E, B);

    k_gemm1<<<nbN, 256, 0, stream>>>(x, W1, dinv, g1, n);
    k_agg1<<<B, 1024, 0, stream>>>(bedge, bstart, btotal, g1, dinv, b1, r1, n);
    k_gemm2<<<nbN, 256, 0, stream>>>(r1, W2, dinv, g2, n);
    k_agg2<<<B, 1024, 0, stream>>>(bedge, bstart, btotal, g2, dinv, b2, out, n);
}

// Round 4
// 1025.021 us; speedup vs baseline: 1.0168x; 1.0168x over previous
//
#include <hip/hip_runtime.h>
#include <math.h>

#define F_IN 512
#define H1 16
#define C_OUT 7
// bucket = dst >> 7 (128 nodes per bucket); pack = (dst&127)<<17 | src (n < 2^17)
#define BSHIFT 7
#define BNODES 128

__global__ void k_zero(int* __restrict__ p, int n) {
    int i = blockIdx.x * 256 + threadIdx.x;
    if (i < n) p[i] = 0;
}

__global__ void k_hist(const int* __restrict__ dst, int* __restrict__ indeg, int E) {
    int e = blockIdx.x * 256 + threadIdx.x;
    if (e < E) atomicAdd(&indeg[dst[e]], 1);
}

__global__ void k_dinv(const int* __restrict__ indeg, float* __restrict__ dinv, int n) {
    int i = blockIdx.x * 256 + threadIdx.x;
    if (i < n) dinv[i] = rsqrtf(1.0f + (float)indeg[i]);
}

// ---------- bucket fill pass 1: per-block bucket histogram (coalesced writes) ----------
__global__ __launch_bounds__(1024) void k_fill_p1(const int* __restrict__ dst,
                                                  int* __restrict__ cnt, int E, int B) {
    __shared__ int lh[1024];              // B <= 1024
    int t = threadIdx.x;
    for (int i = t; i < B; i += 1024) lh[i] = 0;
    __syncthreads();
    int e0 = blockIdx.x * 4096;
#pragma unroll
    for (int k = 0; k < 4; k++) {
        int e = e0 + t + 1024 * k;
        if (e < E) atomicAdd(&lh[dst[e] >> BSHIFT], 1);
    }
    __syncthreads();
    for (int i = t; i < B; i += 1024) cnt[(size_t)blockIdx.x * B + i] = lh[i];
}

// ---------- per-bucket exclusive scan over blocks (no contention) ----------
__global__ __launch_bounds__(256) void k_colscan(const int* __restrict__ cnt,
                                                 int* __restrict__ base,
                                                 int* __restrict__ btotal, int nfb, int B) {
    int b = blockIdx.x;
    int t = threadIdx.x;
    int loc[4];
    int s = 0;
    int j0 = t * 4;                        // nfb <= 1024
#pragma unroll
    for (int k = 0; k < 4; k++) {
        int j = j0 + k;
        int v = (j < nfb) ? cnt[(size_t)j * B + b] : 0;
        loc[k] = s;
        s += v;
    }
    __shared__ int sh[256];
    sh[t] = s;
    __syncthreads();
    for (int off = 1; off < 256; off <<= 1) {
        int v2 = (t >= off) ? sh[t - off] : 0;
        __syncthreads();
        sh[t] += v2;
        __syncthreads();
    }
    int excl = sh[t] - s;
#pragma unroll
    for (int k = 0; k < 4; k++) {
        int j = j0 + k;
        if (j < nfb) base[(size_t)j * B + b] = excl + loc[k];
    }
    if (t == 255) btotal[b] = sh[255];
}

// ---------- exclusive scan of bucket totals ----------
__global__ __launch_bounds__(1024) void k_sscan(const int* __restrict__ btotal,
                                                int* __restrict__ bstart, int B) {
    __shared__ int s[1024];
    int t = threadIdx.x;
    int v = (t < B) ? btotal[t] : 0;
    s[t] = v;
    __syncthreads();
    for (int off = 1; off < 1024; off <<= 1) {
        int x = (t >= off) ? s[t - off] : 0;
        __syncthreads();
        s[t] += x;
        __syncthreads();
    }
    if (t < B) bstart[t] = s[t] - v;
}

// ---------- bucket fill pass 2: LDS bucket-sort + run-coalesced writes ----------
__global__ __launch_bounds__(1024) void k_fill_p2(
    const int* __restrict__ src, const int* __restrict__ dst,
    const int* __restrict__ base, const int* __restrict__ bstart,
    unsigned* __restrict__ bedge, int E, int B) {
    __shared__ int lh[1024];
    __shared__ int scan[1024];            // becomes exclusive local base
    __shared__ int gb[1024];
    __shared__ unsigned lsort[4096];
    __shared__ unsigned short lbk[4096];
    int t = threadIdx.x;
    for (int i = t; i < B; i += 1024) lh[i] = 0;
    __syncthreads();
    int e0 = blockIdx.x * 4096;
    int myb[4], myr[4];
    unsigned myv[4];
#pragma unroll
    for (int k = 0; k < 4; k++) {
        int e = e0 + t + 1024 * k;
        myb[k] = -1;
        if (e < E) {
            int d = dst[e];
            int b = d >> BSHIFT;
            myb[k] = b;
            myv[k] = ((unsigned)(d & (BNODES - 1)) << 17) | (unsigned)src[e];
            myr[k] = atomicAdd(&lh[b], 1);     // LDS ds_add_rtn: fast
        }
    }
    __syncthreads();
    int v = (t < B) ? lh[t] : 0;
    scan[t] = v;
    __syncthreads();
    for (int off = 1; off < 1024; off <<= 1) {
        int x = (t >= off) ? scan[t - off] : 0;
        __syncthreads();
        scan[t] += x;
        __syncthreads();
    }
    scan[t] -= v;                         // exclusive local base
    __syncthreads();
    if (t < B) gb[t] = bstart[t] + base[(size_t)blockIdx.x * B + t];
    __syncthreads();
#pragma unroll
    for (int k = 0; k < 4; k++) {
        if (myb[k] >= 0) {
            int slot = scan[myb[k]] + myr[k];
            lsort[slot] = myv[k];
            lbk[slot] = (unsigned short)myb[k];
        }
    }
    __syncthreads();
    int elim = min(4096, E - e0);
    for (int i = t; i < elim; i += 1024) {
        int b = lbk[i];
        bedge[gb[b] + (i - scan[b])] = lsort[i];   // coalesced within runs
    }
}

// ---------- GEMM1: g1 = dinv * (x @ W1) ----------
__global__ __launch_bounds__(256) void k_gemm1(
    const float* __restrict__ x, const float* __restrict__ W1,
    const float* __restrict__ dinv, float* __restrict__ g1, int n) {
    __shared__ float xs[32 * 257];
    const int tid = threadIdx.x;
    const int rowbase = blockIdx.x * 256;
    const int row = rowbase + tid;

    float acc[H1];
#pragma unroll
    for (int c = 0; c < H1; c++) acc[c] = 0.0f;

    for (int kc = 0; kc < F_IN; kc += 32) {
        __syncthreads();
#pragma unroll
        for (int j = 0; j < 8; j++) {
            int flat = tid + 256 * j;
            int r = flat >> 3;
            int kq = flat & 7;
            int grow = rowbase + r;
            float4 v = make_float4(0.f, 0.f, 0.f, 0.f);
            if (grow < n) v = *(const float4*)(x + (size_t)grow * F_IN + kc + kq * 4);
            xs[(kq * 4 + 0) * 257 + r] = v.x;
            xs[(kq * 4 + 1) * 257 + r] = v.y;
            xs[(kq * 4 + 2) * 257 + r] = v.z;
            xs[(kq * 4 + 3) * 257 + r] = v.w;
        }
        __syncthreads();
#pragma unroll 4
        for (int k = 0; k < 32; k++) {
            float xv = xs[k * 257 + tid];
            const float* w = W1 + (kc + k) * H1;
#pragma unroll
            for (int c = 0; c < H1; c++) acc[c] = fmaf(xv, w[c], acc[c]);
        }
    }

    if (row < n) {
        float d = dinv[row];
#pragma unroll
        for (int c = 0; c < H1; c++) g1[(size_t)row * H1 + c] = acc[c] * d;
    }
}

// ---------- aggregation layer 1: thread-per-edge, LDS accumulate, fused ReLU ----------
__global__ __launch_bounds__(256) void k_agg1(
    const unsigned* __restrict__ bedge, const int* __restrict__ bstart,
    const int* __restrict__ btotal, const float* __restrict__ g1,
    const float* __restrict__ dinv, const float* __restrict__ b1,
    float* __restrict__ r1, int n) {
    __shared__ float acc[BNODES * 17];    // 8704 B
    int t = threadIdx.x;
    int bb = blockIdx.x;
    for (int i = t; i < BNODES * 17; i += 256) acc[i] = 0.f;
    __syncthreads();
    int gs = bstart[bb];
    int ge = gs + btotal[bb];
    for (int e0 = gs + t; e0 < ge; e0 += 512) {
        int e1 = e0 + 256;
        unsigned v0 = bedge[e0];
        bool has1 = (e1 < ge);
        unsigned v1 = has1 ? bedge[e1] : 0u;
        const float4* p0 = (const float4*)(g1 + (size_t)(v0 & 0x1FFFFu) * H1);
        const float4* p1 = (const float4*)(g1 + (size_t)(v1 & 0x1FFFFu) * H1);
        float4 a0 = p0[0], a1 = p0[1], a2 = p0[2], a3 = p0[3];
        float4 c0, c1, c2, c3;
        if (has1) { c0 = p1[0]; c1 = p1[1]; c2 = p1[2]; c3 = p1[3]; }
        int d0 = (int)(v0 >> 17) * 17;
        atomicAdd(&acc[d0 + 0],  a0.x); atomicAdd(&acc[d0 + 1],  a0.y);
        atomicAdd(&acc[d0 + 2],  a0.z); atomicAdd(&acc[d0 + 3],  a0.w);
        atomicAdd(&acc[d0 + 4],  a1.x); atomicAdd(&acc[d0 + 5],  a1.y);
        atomicAdd(&acc[d0 + 6],  a1.z); atomicAdd(&acc[d0 + 7],  a1.w);
        atomicAdd(&acc[d0 + 8],  a2.x); atomicAdd(&acc[d0 + 9],  a2.y);
        atomicAdd(&acc[d0 + 10], a2.z); atomicAdd(&acc[d0 + 11], a2.w);
        atomicAdd(&acc[d0 + 12], a3.x); atomicAdd(&acc[d0 + 13], a3.y);
        atomicAdd(&acc[d0 + 14], a3.z); atomicAdd(&acc[d0 + 15], a3.w);
        if (has1) {
            int d1 = (int)(v1 >> 17) * 17;
            atomicAdd(&acc[d1 + 0],  c0.x); atomicAdd(&acc[d1 + 1],  c0.y);
            atomicAdd(&acc[d1 + 2],  c0.z); atomicAdd(&acc[d1 + 3],  c0.w);
            atomicAdd(&acc[d1 + 4],  c1.x); atomicAdd(&acc[d1 + 5],  c1.y);
            atomicAdd(&acc[d1 + 6],  c1.z); atomicAdd(&acc[d1 + 7],  c1.w);
            atomicAdd(&acc[d1 + 8],  c2.x); atomicAdd(&acc[d1 + 9],  c2.y);
            atomicAdd(&acc[d1 + 10], c2.z); atomicAdd(&acc[d1 + 11], c2.w);
            atomicAdd(&acc[d1 + 12], c3.x); atomicAdd(&acc[d1 + 13], c3.y);
            atomicAdd(&acc[d1 + 14], c3.z); atomicAdd(&acc[d1 + 15], c3.w);
        }
    }
    __syncthreads();
    int nodebase = bb << BSHIFT;
    for (int i = t; i < BNODES * 16; i += 256) {
        int dl = i >> 4, cc = i & 15;
        int node = nodebase + dl;
        if (node < n) {
            float sum = acc[dl * 17 + cc] + g1[(size_t)node * H1 + cc];  // + self-loop
            float val = fmaf(dinv[node], sum, b1[cc]);
            r1[(size_t)node * H1 + cc] = fmaxf(val, 0.f);
        }
    }
}

// ---------- GEMM2: g2 = dinv * (r1 @ W2), row stride 8, col 7 = 0 ----------
__global__ __launch_bounds__(256) void k_gemm2(
    const float* __restrict__ r1, const float* __restrict__ W2,
    const float* __restrict__ dinv, float* __restrict__ g2, int n) {
    __shared__ float xs[16 * 257];
    const int tid = threadIdx.x;
    const int rowbase = blockIdx.x * 256;
    const int row = rowbase + tid;

#pragma unroll
    for (int j = 0; j < 4; j++) {
        int flat = tid + 256 * j;
        int r = flat >> 2;
        int kq = flat & 3;
        int grow = rowbase + r;
        float4 v = make_float4(0.f, 0.f, 0.f, 0.f);
        if (grow < n) v = *(const float4*)(r1 + (size_t)grow * H1 + kq * 4);
        xs[(kq * 4 + 0) * 257 + r] = v.x;
        xs[(kq * 4 + 1) * 257 + r] = v.y;
        xs[(kq * 4 + 2) * 257 + r] = v.z;
        xs[(kq * 4 + 3) * 257 + r] = v.w;
    }
    __syncthreads();

    float acc[C_OUT];
#pragma unroll
    for (int c = 0; c < C_OUT; c++) acc[c] = 0.0f;
#pragma unroll
    for (int k = 0; k < H1; k++) {
        float xv = xs[k * 257 + tid];
        const float* w = W2 + k * C_OUT;
#pragma unroll
        for (int c = 0; c < C_OUT; c++) acc[c] = fmaf(xv, w[c], acc[c]);
    }

    if (row < n) {
        float d = dinv[row];
#pragma unroll
        for (int c = 0; c < C_OUT; c++) g2[(size_t)row * 8 + c] = acc[c] * d;
        g2[(size_t)row * 8 + 7] = 0.0f;
    }
}

// ---------- aggregation layer 2: thread-per-edge + fused log_softmax ----------
__global__ __launch_bounds__(256) void k_agg2(
    const unsigned* __restrict__ bedge, const int* __restrict__ bstart,
    const int* __restrict__ btotal, const float* __restrict__ g2,
    const float* __restrict__ dinv, const float* __restrict__ b2,
    float* __restrict__ out, int n) {
    __shared__ float acc[BNODES * 9];     // 4608 B
    int t = threadIdx.x;
    int bb = blockIdx.x;
    for (int i = t; i < BNODES * 9; i += 256) acc[i] = 0.f;
    __syncthreads();
    int gs = bstart[bb];
    int ge = gs + btotal[bb];
    for (int e0 = gs + t; e0 < ge; e0 += 512) {
        int e1 = e0 + 256;
        unsigned v0 = bedge[e0];
        bool has1 = (e1 < ge);
        unsigned v1 = has1 ? bedge[e1] : 0u;
        const float4* p0 = (const float4*)(g2 + (size_t)(v0 & 0x1FFFFu) * 8);
        const float4* p1 = (const float4*)(g2 + (size_t)(v1 & 0x1FFFFu) * 8);
        float4 a0 = p0[0], a1 = p0[1];
        float4 c0, c1;
        if (has1) { c0 = p1[0]; c1 = p1[1]; }
        int d0 = (int)(v0 >> 17) * 9;
        atomicAdd(&acc[d0 + 0], a0.x); atomicAdd(&acc[d0 + 1], a0.y);
        atomicAdd(&acc[d0 + 2], a0.z); atomicAdd(&acc[d0 + 3], a0.w);
        atomicAdd(&acc[d0 + 4], a1.x); atomicAdd(&acc[d0 + 5], a1.y);
        atomicAdd(&acc[d0 + 6], a1.z);
        if (has1) {
            int d1 = (int)(v1 >> 17) * 9;
            atomicAdd(&acc[d1 + 0], c0.x); atomicAdd(&acc[d1 + 1], c0.y);
            atomicAdd(&acc[d1 + 2], c0.z); atomicAdd(&acc[d1 + 3], c0.w);
            atomicAdd(&acc[d1 + 4], c1.x); atomicAdd(&acc[d1 + 5], c1.y);
            atomicAdd(&acc[d1 + 6], c1.z);
        }
    }
    __syncthreads();
    int nodebase = bb << BSHIFT;
    for (int i = t; i < BNODES * 8; i += 256) {
        int dl = i >> 3, c = i & 7;
        int node = nodebase + dl;
        float val = 0.f;
        bool ok = (node < n);
        if (ok) {
            float sum = acc[dl * 9 + c] + ((c < C_OUT) ? g2[(size_t)node * 8 + c] : 0.f);
            float bc = (c < C_OUT) ? b2[c] : 0.f;
            val = fmaf(dinv[node], sum, bc);
        }
        float vv = (c < C_OUT) ? val : -1e30f;
        float m = vv;
#pragma unroll
        for (int o = 1; o < 8; o <<= 1) m = fmaxf(m, __shfl_xor(m, o, 8));
        float ex = (c < C_OUT) ? expf(val - m) : 0.f;
        float se = ex;
#pragma unroll
        for (int o = 1; o < 8; o <<= 1) se += __shfl_xor(se, o, 8);
        float l = logf(se) + m;
        if (ok && c < C_OUT) out[(size_t)node * C_OUT + c] = val - l;
    }
}

extern "C" void kernel_launch(void* const* d_in, const int* in_sizes, int n_in,
                              void* d_out, int out_size, void* d_ws, size_t ws_size,
                              hipStream_t stream) {
    const float* x  = (const float*)d_in[0];
    const int* ei   = (const int*)d_in[1];
    const float* W1 = (const float*)d_in[2];
    const float* b1 = (const float*)d_in[3];
    const float* W2 = (const float*)d_in[4];
    const float* b2 = (const float*)d_in[5];
    float* out = (float*)d_out;

    const int n = in_sizes[0] / F_IN;     // 100000
    const int E = in_sizes[1] / 2;        // 3200000
    const int* src = ei;
    const int* dst = ei + E;

    const int B   = (n + BNODES - 1) >> BSHIFT;   // 782 buckets (<=1024)
    const int nfb = (E + 4095) >> 12;             // 782 fill blocks (<=1024)

    // workspace (4-byte units)
    int*   indeg  = (int*)d_ws;                            // n
    float* dinv   = (float*)(indeg + n);                   // n
    float* g1     = dinv + n;                              // 16n (g2 aliases low 8n)
    float* r1     = g1 + (size_t)16 * n;                   // 16n
    int*   cnt    = (int*)(r1 + (size_t)16 * n);           // nfb*B
    int*   base   = cnt + (size_t)nfb * B;                 // nfb*B
    int*   btotal = base + (size_t)nfb * B;                // B
    int*   bstart = btotal + B;                            // B
    unsigned* bedge = (unsigned*)(bstart + B);             // E
    float* g2 = g1;

    const int nbN = (n + 255) / 256;
    const int nbE = (E + 255) / 256;

    k_zero<<<nbN, 256, 0, stream>>>(indeg, n);
    k_hist<<<nbE, 256, 0, stream>>>(dst, indeg, E);
    k_dinv<<<nbN, 256, 0, stream>>>(indeg, dinv, n);

    k_fill_p1<<<nfb, 1024, 0, stream>>>(dst, cnt, E, B);
    k_colscan<<<B, 256, 0, stream>>>(cnt, base, btotal, nfb, B);
    k_sscan<<<1, 1024, 0, stream>>>(btotal, bstart, B);
    k_fill_p2<<<nfb, 1024, 0, stream>>>(src, dst, base, bstart, bedge, E, B);

    k_gemm1<<<nbN, 256, 0, stream>>>(x, W1, dinv, g1, n);
    k_agg1<<<B, 256, 0, stream>>>(bedge, bstart, btotal, g1, dinv, b1, r1, n);
    k_gemm2<<<nbN, 256, 0, stream>>>(r1, W2, dinv, g2, n);
    k_agg2<<<B, 256, 0, stream>>>(bedge, bstart, btotal, g2, dinv, b2, out, n);
}

// Round 5
// 658.161 us; speedup vs baseline: 1.5836x; 1.5574x over previous
//
#include <hip/hip_runtime.h>
#include <math.h>

#define F_IN 512
#define H1 16
#define C_OUT 7
#define BSHIFT 7
#define BNODES 128
#define SRCMASK 0x1FFFFu
#define P3CAP 5120

__global__ void k_zero(int* __restrict__ p, int n) {
    int i = blockIdx.x * 256 + threadIdx.x;
    if (i < n) p[i] = 0;
}

__global__ void k_hist(const int* __restrict__ dst, int* __restrict__ indeg, int E) {
    int e = blockIdx.x * 256 + threadIdx.x;
    if (e < E) atomicAdd(&indeg[dst[e]], 1);
}

__global__ void k_dinv(const int* __restrict__ indeg, float* __restrict__ dinv, int n) {
    int i = blockIdx.x * 256 + threadIdx.x;
    if (i < n) dinv[i] = rsqrtf(1.0f + (float)indeg[i]);
}

// ---------- node-level exclusive scan (rowptr) ----------
__global__ void k_scan1(const int* __restrict__ indeg, int* __restrict__ excl,
                        int* __restrict__ blocksum, int n) {
    __shared__ int s[256];
    int i = blockIdx.x * 256 + threadIdx.x;
    int v = (i < n) ? indeg[i] : 0;
    s[threadIdx.x] = v;
    __syncthreads();
    for (int off = 1; off < 256; off <<= 1) {
        int t = (threadIdx.x >= off) ? s[threadIdx.x - off] : 0;
        __syncthreads();
        s[threadIdx.x] += t;
        __syncthreads();
    }
    if (i < n) excl[i] = s[threadIdx.x] - v;
    if (threadIdx.x == 255) blocksum[blockIdx.x] = s[255];
}

__global__ void k_scan2(int* __restrict__ blocksum, int nb) {
    __shared__ int s[512];
    int t = threadIdx.x;
    int v = (t < nb) ? blocksum[t] : 0;
    s[t] = v;
    __syncthreads();
    for (int off = 1; off < 512; off <<= 1) {
        int x = (t >= off) ? s[t - off] : 0;
        __syncthreads();
        s[t] += x;
        __syncthreads();
    }
    if (t < nb) blocksum[t] = s[t] - v;
}

__global__ void k_scan3(int* __restrict__ rowptr, const int* __restrict__ blocksum, int n) {
    int i = blockIdx.x * 256 + threadIdx.x;
    if (i < n) rowptr[i] += blocksum[blockIdx.x];
}

// ---------- bucket fill pass 1: per-block bucket histogram ----------
__global__ __launch_bounds__(1024) void k_fill_p1(const int* __restrict__ dst,
                                                  int* __restrict__ cnt, int E, int B) {
    __shared__ int lh[1024];
    int t = threadIdx.x;
    for (int i = t; i < B; i += 1024) lh[i] = 0;
    __syncthreads();
    int e0 = blockIdx.x * 4096;
#pragma unroll
    for (int k = 0; k < 4; k++) {
        int e = e0 + t + 1024 * k;
        if (e < E) atomicAdd(&lh[dst[e] >> BSHIFT], 1);
    }
    __syncthreads();
    for (int i = t; i < B; i += 1024) cnt[(size_t)blockIdx.x * B + i] = lh[i];
}

// ---------- per-bucket exclusive scan over fill blocks ----------
__global__ __launch_bounds__(256) void k_colscan(const int* __restrict__ cnt,
                                                 int* __restrict__ base, int nfb, int B) {
    int b = blockIdx.x;
    int t = threadIdx.x;
    int loc[4];
    int s = 0;
    int j0 = t * 4;
#pragma unroll
    for (int k = 0; k < 4; k++) {
        int j = j0 + k;
        int v = (j < nfb) ? cnt[(size_t)j * B + b] : 0;
        loc[k] = s;
        s += v;
    }
    __shared__ int sh[256];
    sh[t] = s;
    __syncthreads();
    for (int off = 1; off < 256; off <<= 1) {
        int v2 = (t >= off) ? sh[t - off] : 0;
        __syncthreads();
        sh[t] += v2;
        __syncthreads();
    }
    int excl = sh[t] - s;
#pragma unroll
    for (int k = 0; k < 4; k++) {
        int j = j0 + k;
        if (j < nfb) base[(size_t)j * B + b] = excl + loc[k];
    }
}

// ---------- bucket fill pass 2: LDS bucket-sort + run-coalesced writes ----------
__global__ __launch_bounds__(1024) void k_fill_p2(
    const int* __restrict__ src, const int* __restrict__ dst,
    const int* __restrict__ base, const int* __restrict__ rowptr,
    unsigned* __restrict__ bedge, int E, int B, int n) {
    __shared__ int lh[1024];
    __shared__ int scan[1024];
    __shared__ int gb[1024];
    __shared__ unsigned lsort[4096];
    __shared__ unsigned short lbk[4096];
    int t = threadIdx.x;
    for (int i = t; i < B; i += 1024) lh[i] = 0;
    __syncthreads();
    int e0 = blockIdx.x * 4096;
    int myb[4], myr[4];
    unsigned myv[4];
#pragma unroll
    for (int k = 0; k < 4; k++) {
        int e = e0 + t + 1024 * k;
        myb[k] = -1;
        if (e < E) {
            int d = dst[e];
            int b = d >> BSHIFT;
            myb[k] = b;
            myv[k] = ((unsigned)(d & (BNODES - 1)) << 17) | (unsigned)src[e];
            myr[k] = atomicAdd(&lh[b], 1);
        }
    }
    __syncthreads();
    int v = (t < B) ? lh[t] : 0;
    scan[t] = v;
    __syncthreads();
    for (int off = 1; off < 1024; off <<= 1) {
        int x = (t >= off) ? scan[t - off] : 0;
        __syncthreads();
        scan[t] += x;
        __syncthreads();
    }
    scan[t] -= v;
    __syncthreads();
    if (t < B) gb[t] = rowptr[t << BSHIFT] + base[(size_t)blockIdx.x * B + t];
    __syncthreads();
#pragma unroll
    for (int k = 0; k < 4; k++) {
        if (myb[k] >= 0) {
            int slot = scan[myb[k]] + myr[k];
            lsort[slot] = myv[k];
            lbk[slot] = (unsigned short)myb[k];
        }
    }
    __syncthreads();
    int elim = min(4096, E - e0);
    for (int i = t; i < elim; i += 1024) {
        int b = lbk[i];
        bedge[gb[b] + (i - scan[b])] = lsort[i];
    }
}

// ---------- fill pass 3: per-bucket counting sort by node -> csr_src ----------
__global__ __launch_bounds__(256) void k_fill_p3(
    const int* __restrict__ rowptr, const unsigned* __restrict__ bedge,
    int* __restrict__ csr_src, int n, int E) {
    __shared__ int off[BNODES];
    __shared__ int lh[BNODES];
    __shared__ int lsort[P3CAP];
    int t = threadIdx.x;
    int bb = blockIdx.x;
    int nodebase = bb << BSHIFT;
    int gs = rowptr[nodebase];
    int nend = nodebase + BNODES;
    int ge = (nend >= n) ? E : rowptr[nend];
    for (int i = t; i < BNODES; i += 256) {
        int nd = nodebase + i;
        off[i] = (nd < n) ? rowptr[nd] - gs : 0;
        lh[i] = 0;
    }
    __syncthreads();
    for (int e = gs + t; e < ge; e += 256) {
        unsigned v = bedge[e];
        int dl = (int)(v >> 17);
        int rank = atomicAdd(&lh[dl], 1);
        int pos = off[dl] + rank;
        int sv = (int)(v & SRCMASK);
        if (pos < P3CAP) lsort[pos] = sv;
        else csr_src[gs + pos] = sv;          // overflow fallback (rare)
    }
    __syncthreads();
    int lim = min(ge - gs, P3CAP);
    for (int i = t; i < lim; i += 256) csr_src[gs + i] = lsort[i];
}

// ---------- GEMM1: g1 = dinv * (x @ W1), K-split-4, no staging barriers ----------
__global__ __launch_bounds__(256) void k_gemm1(
    const float* __restrict__ x, const float* __restrict__ W1,
    const float* __restrict__ dinv, float* __restrict__ g1, int n) {
    __shared__ float sh[4][64][17];
    int t = threadIdx.x;
    int q = t >> 6;                 // wave id = K-quarter (uniform per wave)
    int r = t & 63;
    int row = blockIdx.x * 64 + r;
    int crow = min(row, n - 1);

    float acc[H1];
#pragma unroll
    for (int c = 0; c < H1; c++) acc[c] = 0.0f;

    const float4* xp = (const float4*)(x + (size_t)crow * F_IN + q * 128);
#pragma unroll 2
    for (int k16 = 0; k16 < 8; k16++) {      // 16 K per step: one full 64B line per lane
        float4 v0 = xp[k16 * 4 + 0];
        float4 v1 = xp[k16 * 4 + 1];
        float4 v2 = xp[k16 * 4 + 2];
        float4 v3 = xp[k16 * 4 + 3];
        const float* w = W1 + (q * 128 + k16 * 16) * H1;   // wave-uniform -> s_load
        float xv[16] = {v0.x, v0.y, v0.z, v0.w, v1.x, v1.y, v1.z, v1.w,
                        v2.x, v2.y, v2.z, v2.w, v3.x, v3.y, v3.z, v3.w};
#pragma unroll
        for (int k = 0; k < 16; k++)
#pragma unroll
            for (int c = 0; c < H1; c++)
                acc[c] = fmaf(xv[k], w[k * H1 + c], acc[c]);
    }
#pragma unroll
    for (int c = 0; c < H1; c++) sh[q][r][c] = acc[c];
    __syncthreads();

    int r2 = t >> 2, cb = (t & 3) * 4;
    int orow = blockIdx.x * 64 + r2;
    if (orow < n) {
        float d = dinv[orow];
        float4 o;
        o.x = (sh[0][r2][cb + 0] + sh[1][r2][cb + 0] + sh[2][r2][cb + 0] + sh[3][r2][cb + 0]) * d;
        o.y = (sh[0][r2][cb + 1] + sh[1][r2][cb + 1] + sh[2][r2][cb + 1] + sh[3][r2][cb + 1]) * d;
        o.z = (sh[0][r2][cb + 2] + sh[1][r2][cb + 2] + sh[2][r2][cb + 2] + sh[3][r2][cb + 2]) * d;
        o.w = (sh[0][r2][cb + 3] + sh[1][r2][cb + 3] + sh[2][r2][cb + 3] + sh[3][r2][cb + 3]) * d;
        *(float4*)(g1 + (size_t)orow * H1 + cb) = o;
    }
}

// ---------- aggregation 1: CSR pull, 16 lanes/node, fused ReLU ----------
__global__ __launch_bounds__(256) void k_agg1(
    const int* __restrict__ rowptr, const int* __restrict__ indeg,
    const int* __restrict__ csr_src, const float* __restrict__ g1,
    const float* __restrict__ dinv, const float* __restrict__ b1,
    float* __restrict__ r1, int n) {
    int t = threadIdx.x;
    int node = blockIdx.x * 16 + (t >> 4);
    int c = t & 15;
    if (node >= n) return;
    int start = rowptr[node];
    int end = start + indeg[node];
    float s0 = g1[(size_t)node * H1 + c];    // self-loop
    float s1 = 0.f, s2 = 0.f, s3 = 0.f, s4 = 0.f, s5 = 0.f, s6 = 0.f, s7 = 0.f;
    int i = start;
    for (; i + 8 <= end; i += 8) {
        int a0 = csr_src[i + 0], a1 = csr_src[i + 1], a2 = csr_src[i + 2], a3 = csr_src[i + 3];
        int a4 = csr_src[i + 4], a5 = csr_src[i + 5], a6 = csr_src[i + 6], a7 = csr_src[i + 7];
        s0 += g1[(size_t)a0 * H1 + c];
        s1 += g1[(size_t)a1 * H1 + c];
        s2 += g1[(size_t)a2 * H1 + c];
        s3 += g1[(size_t)a3 * H1 + c];
        s4 += g1[(size_t)a4 * H1 + c];
        s5 += g1[(size_t)a5 * H1 + c];
        s6 += g1[(size_t)a6 * H1 + c];
        s7 += g1[(size_t)a7 * H1 + c];
    }
    for (; i < end; i++) s0 += g1[(size_t)csr_src[i] * H1 + c];
    float sum = ((s0 + s1) + (s2 + s3)) + ((s4 + s5) + (s6 + s7));
    float val = fmaf(dinv[node], sum, b1[c]);
    r1[(size_t)node * H1 + c] = fmaxf(val, 0.f);
}

// ---------- GEMM2: g2 = dinv * (r1 @ W2), row stride 8, col 7 = 0 ----------
__global__ __launch_bounds__(256) void k_gemm2(
    const float* __restrict__ r1, const float* __restrict__ W2,
    const float* __restrict__ dinv, float* __restrict__ g2, int n) {
    __shared__ float xs[16 * 257];
    const int tid = threadIdx.x;
    const int rowbase = blockIdx.x * 256;
    const int row = rowbase + tid;

#pragma unroll
    for (int j = 0; j < 4; j++) {
        int flat = tid + 256 * j;
        int r = flat >> 2;
        int kq = flat & 3;
        int grow = rowbase + r;
        float4 v = make_float4(0.f, 0.f, 0.f, 0.f);
        if (grow < n) v = *(const float4*)(r1 + (size_t)grow * H1 + kq * 4);
        xs[(kq * 4 + 0) * 257 + r] = v.x;
        xs[(kq * 4 + 1) * 257 + r] = v.y;
        xs[(kq * 4 + 2) * 257 + r] = v.z;
        xs[(kq * 4 + 3) * 257 + r] = v.w;
    }
    __syncthreads();

    float acc[C_OUT];
#pragma unroll
    for (int c = 0; c < C_OUT; c++) acc[c] = 0.0f;
#pragma unroll
    for (int k = 0; k < H1; k++) {
        float xv = xs[k * 257 + tid];
        const float* w = W2 + k * C_OUT;
#pragma unroll
        for (int c = 0; c < C_OUT; c++) acc[c] = fmaf(xv, w[c], acc[c]);
    }

    if (row < n) {
        float d = dinv[row];
#pragma unroll
        for (int c = 0; c < C_OUT; c++) g2[(size_t)row * 8 + c] = acc[c] * d;
        g2[(size_t)row * 8 + 7] = 0.0f;
    }
}

// ---------- aggregation 2: CSR pull, 8 lanes/node + fused log_softmax ----------
__global__ __launch_bounds__(256) void k_agg2(
    const int* __restrict__ rowptr, const int* __restrict__ indeg,
    const int* __restrict__ csr_src, const float* __restrict__ g2,
    const float* __restrict__ dinv, const float* __restrict__ b2,
    float* __restrict__ out, int n) {
    int t = threadIdx.x;
    int node = blockIdx.x * 32 + (t >> 3);
    int c = t & 7;
    if (node >= n) return;
    int start = rowptr[node];
    int end = start + indeg[node];
    float s0 = (c < C_OUT) ? g2[(size_t)node * 8 + c] : 0.f;   // self-loop
    float s1 = 0.f, s2 = 0.f, s3 = 0.f, s4 = 0.f, s5 = 0.f, s6 = 0.f, s7 = 0.f;
    int i = start;
    for (; i + 8 <= end; i += 8) {
        int a0 = csr_src[i + 0], a1 = csr_src[i + 1], a2 = csr_src[i + 2], a3 = csr_src[i + 3];
        int a4 = csr_src[i + 4], a5 = csr_src[i + 5], a6 = csr_src[i + 6], a7 = csr_src[i + 7];
        s0 += g2[(size_t)a0 * 8 + c];
        s1 += g2[(size_t)a1 * 8 + c];
        s2 += g2[(size_t)a2 * 8 + c];
        s3 += g2[(size_t)a3 * 8 + c];
        s4 += g2[(size_t)a4 * 8 + c];
        s5 += g2[(size_t)a5 * 8 + c];
        s6 += g2[(size_t)a6 * 8 + c];
        s7 += g2[(size_t)a7 * 8 + c];
    }
    for (; i < end; i++) s0 += g2[(size_t)csr_src[i] * 8 + c];
    float sum = ((s0 + s1) + (s2 + s3)) + ((s4 + s5) + (s6 + s7));
    float bc = (c < C_OUT) ? b2[c] : 0.f;
    float val = fmaf(dinv[node], sum, bc);

    float vv = (c < C_OUT) ? val : -1e30f;
    float m = vv;
#pragma unroll
    for (int o = 1; o < 8; o <<= 1) m = fmaxf(m, __shfl_xor(m, o, 8));
    float ex = (c < C_OUT) ? expf(val - m) : 0.f;
    float se = ex;
#pragma unroll
    for (int o = 1; o < 8; o <<= 1) se += __shfl_xor(se, o, 8);
    float l = logf(se) + m;
    if (c < C_OUT) out[(size_t)node * C_OUT + c] = val - l;
}

extern "C" void kernel_launch(void* const* d_in, const int* in_sizes, int n_in,
                              void* d_out, int out_size, void* d_ws, size_t ws_size,
                              hipStream_t stream) {
    const float* x  = (const float*)d_in[0];
    const int* ei   = (const int*)d_in[1];
    const float* W1 = (const float*)d_in[2];
    const float* b1 = (const float*)d_in[3];
    const float* W2 = (const float*)d_in[4];
    const float* b2 = (const float*)d_in[5];
    float* out = (float*)d_out;

    const int n = in_sizes[0] / F_IN;     // 100000
    const int E = in_sizes[1] / 2;        // 3200000
    const int* src = ei;
    const int* dst = ei + E;

    const int B   = (n + BNODES - 1) >> BSHIFT;   // 782
    const int nfb = (E + 4095) >> 12;             // 782

    // workspace (4-byte units)
    int*   indeg    = (int*)d_ws;                          // n
    int*   rowptr   = indeg + n;                           // n
    float* dinv     = (float*)(rowptr + n);                // n
    int*   blocksum = (int*)(dinv + n);                    // 512
    int*   cnt      = blocksum + 512;                      // nfb*B
    int*   base     = cnt + (size_t)nfb * B;               // nfb*B
    float* g1       = (float*)(base + (size_t)nfb * B);    // 16n (g2 aliases low 8n)
    float* r1       = g1 + (size_t)16 * n;                 // 16n
    unsigned* bedge = (unsigned*)(r1 + (size_t)16 * n);    // E
    int*   csr_src  = (int*)(bedge + E);                   // E
    float* g2 = g1;

    const int nbN = (n + 255) / 256;   // 391
    const int nbE = (E + 255) / 256;   // 12500

    k_zero<<<nbN, 256, 0, stream>>>(indeg, n);
    k_hist<<<nbE, 256, 0, stream>>>(dst, indeg, E);
    k_dinv<<<nbN, 256, 0, stream>>>(indeg, dinv, n);
    k_scan1<<<nbN, 256, 0, stream>>>(indeg, rowptr, blocksum, n);
    k_scan2<<<1, 512, 0, stream>>>(blocksum, nbN);
    k_scan3<<<nbN, 256, 0, stream>>>(rowptr, blocksum, n);

    k_fill_p1<<<nfb, 1024, 0, stream>>>(dst, cnt, E, B);
    k_colscan<<<B, 256, 0, stream>>>(cnt, base, nfb, B);
    k_fill_p2<<<nfb, 1024, 0, stream>>>(src, dst, base, rowptr, bedge, E, B, n);
    k_fill_p3<<<B, 256, 0, stream>>>(rowptr, bedge, csr_src, n, E);

    k_gemm1<<<(n + 63) / 64, 256, 0, stream>>>(x, W1, dinv, g1, n);
    k_agg1<<<(n + 15) / 16, 256, 0, stream>>>(rowptr, indeg, csr_src, g1, dinv, b1, r1, n);
    k_gemm2<<<nbN, 256, 0, stream>>>(r1, W2, dinv, g2, n);
    k_agg2<<<(n + 31) / 32, 256, 0, stream>>>(rowptr, indeg, csr_src, g2, dinv, b2, out, n);
}

// Round 6
// 582.527 us; speedup vs baseline: 1.7892x; 1.1298x over previous
//
#include <hip/hip_runtime.h>
#include <math.h>

#define F_IN 512
#define H1 16
#define C_OUT 7
#define BSHIFT 7
#define BNODES 128
#define SRCMASK 0x1FFFFu
#define P3CAP 5120

__global__ void k_zero(int* __restrict__ p, int n) {
    int i = blockIdx.x * 256 + threadIdx.x;
    if (i < n) p[i] = 0;
}

__global__ void k_hist(const int* __restrict__ dst, int* __restrict__ indeg, int E) {
    int e = blockIdx.x * 256 + threadIdx.x;
    if (e < E) atomicAdd(&indeg[dst[e]], 1);
}

__global__ void k_dinv(const int* __restrict__ indeg, float* __restrict__ dinv, int n) {
    int i = blockIdx.x * 256 + threadIdx.x;
    if (i < n) dinv[i] = rsqrtf(1.0f + (float)indeg[i]);
}

// ---------- node-level exclusive scan (rowptr) ----------
__global__ void k_scan1(const int* __restrict__ indeg, int* __restrict__ excl,
                        int* __restrict__ blocksum, int n) {
    __shared__ int s[256];
    int i = blockIdx.x * 256 + threadIdx.x;
    int v = (i < n) ? indeg[i] : 0;
    s[threadIdx.x] = v;
    __syncthreads();
    for (int off = 1; off < 256; off <<= 1) {
        int t = (threadIdx.x >= off) ? s[threadIdx.x - off] : 0;
        __syncthreads();
        s[threadIdx.x] += t;
        __syncthreads();
    }
    if (i < n) excl[i] = s[threadIdx.x] - v;
    if (threadIdx.x == 255) blocksum[blockIdx.x] = s[255];
}

__global__ void k_scan2(int* __restrict__ blocksum, int nb) {
    __shared__ int s[512];
    int t = threadIdx.x;
    int v = (t < nb) ? blocksum[t] : 0;
    s[t] = v;
    __syncthreads();
    for (int off = 1; off < 512; off <<= 1) {
        int x = (t >= off) ? s[t - off] : 0;
        __syncthreads();
        s[t] += x;
        __syncthreads();
    }
    if (t < nb) blocksum[t] = s[t] - v;
}

__global__ void k_scan3(int* __restrict__ rowptr, const int* __restrict__ blocksum, int n) {
    int i = blockIdx.x * 256 + threadIdx.x;
    if (i < n) rowptr[i] += blocksum[blockIdx.x];
}

// ---------- bucket fill pass 1: per-block bucket histogram ----------
__global__ __launch_bounds__(1024) void k_fill_p1(const int* __restrict__ dst,
                                                  int* __restrict__ cnt, int E, int B) {
    __shared__ int lh[1024];
    int t = threadIdx.x;
    for (int i = t; i < B; i += 1024) lh[i] = 0;
    __syncthreads();
    int e0 = blockIdx.x * 4096;
#pragma unroll
    for (int k = 0; k < 4; k++) {
        int e = e0 + t + 1024 * k;
        if (e < E) atomicAdd(&lh[dst[e] >> BSHIFT], 1);
    }
    __syncthreads();
    for (int i = t; i < B; i += 1024) cnt[(size_t)blockIdx.x * B + i] = lh[i];
}

// ---------- per-bucket exclusive scan over fill blocks ----------
__global__ __launch_bounds__(256) void k_colscan(const int* __restrict__ cnt,
                                                 int* __restrict__ base, int nfb, int B) {
    int b = blockIdx.x;
    int t = threadIdx.x;
    int loc[4];
    int s = 0;
    int j0 = t * 4;
#pragma unroll
    for (int k = 0; k < 4; k++) {
        int j = j0 + k;
        int v = (j < nfb) ? cnt[(size_t)j * B + b] : 0;
        loc[k] = s;
        s += v;
    }
    __shared__ int sh[256];
    sh[t] = s;
    __syncthreads();
    for (int off = 1; off < 256; off <<= 1) {
        int v2 = (t >= off) ? sh[t - off] : 0;
        __syncthreads();
        sh[t] += v2;
        __syncthreads();
    }
    int excl = sh[t] - s;
#pragma unroll
    for (int k = 0; k < 4; k++) {
        int j = j0 + k;
        if (j < nfb) base[(size_t)j * B + b] = excl + loc[k];
    }
}

// ---------- bucket fill pass 2: LDS bucket-sort + run-coalesced writes ----------
__global__ __launch_bounds__(1024) void k_fill_p2(
    const int* __restrict__ src, const int* __restrict__ dst,
    const int* __restrict__ base, const int* __restrict__ rowptr,
    unsigned* __restrict__ bedge, int E, int B, int n) {
    __shared__ int lh[1024];
    __shared__ int scan[1024];
    __shared__ int gb[1024];
    __shared__ unsigned lsort[4096];
    __shared__ unsigned short lbk[4096];
    int t = threadIdx.x;
    for (int i = t; i < B; i += 1024) lh[i] = 0;
    __syncthreads();
    int e0 = blockIdx.x * 4096;
    int myb[4], myr[4];
    unsigned myv[4];
#pragma unroll
    for (int k = 0; k < 4; k++) {
        int e = e0 + t + 1024 * k;
        myb[k] = -1;
        if (e < E) {
            int d = dst[e];
            int b = d >> BSHIFT;
            myb[k] = b;
            myv[k] = ((unsigned)(d & (BNODES - 1)) << 17) | (unsigned)src[e];
            myr[k] = atomicAdd(&lh[b], 1);
        }
    }
    __syncthreads();
    int v = (t < B) ? lh[t] : 0;
    scan[t] = v;
    __syncthreads();
    for (int off = 1; off < 1024; off <<= 1) {
        int x = (t >= off) ? scan[t - off] : 0;
        __syncthreads();
        scan[t] += x;
        __syncthreads();
    }
    scan[t] -= v;
    __syncthreads();
    if (t < B) gb[t] = rowptr[t << BSHIFT] + base[(size_t)blockIdx.x * B + t];
    __syncthreads();
#pragma unroll
    for (int k = 0; k < 4; k++) {
        if (myb[k] >= 0) {
            int slot = scan[myb[k]] + myr[k];
            lsort[slot] = myv[k];
            lbk[slot] = (unsigned short)myb[k];
        }
    }
    __syncthreads();
    int elim = min(4096, E - e0);
    for (int i = t; i < elim; i += 1024) {
        int b = lbk[i];
        bedge[gb[b] + (i - scan[b])] = lsort[i];
    }
}

// ---------- fill pass 3: per-bucket counting sort by node -> csr_src ----------
__global__ __launch_bounds__(256) void k_fill_p3(
    const int* __restrict__ rowptr, const unsigned* __restrict__ bedge,
    int* __restrict__ csr_src, int n, int E) {
    __shared__ int off[BNODES];
    __shared__ int lh[BNODES];
    __shared__ int lsort[P3CAP];
    int t = threadIdx.x;
    int bb = blockIdx.x;
    int nodebase = bb << BSHIFT;
    int gs = rowptr[nodebase];
    int nend = nodebase + BNODES;
    int ge = (nend >= n) ? E : rowptr[nend];
    for (int i = t; i < BNODES; i += 256) {
        int nd = nodebase + i;
        off[i] = (nd < n) ? rowptr[nd] - gs : 0;
        lh[i] = 0;
    }
    __syncthreads();
    for (int e = gs + t; e < ge; e += 256) {
        unsigned v = bedge[e];
        int dl = (int)(v >> 17);
        int rank = atomicAdd(&lh[dl], 1);
        int pos = off[dl] + rank;
        int sv = (int)(v & SRCMASK);
        if (pos < P3CAP) lsort[pos] = sv;
        else csr_src[gs + pos] = sv;
    }
    __syncthreads();
    int lim = min(ge - gs, P3CAP);
    for (int i = t; i < lim; i += 256) csr_src[gs + i] = lsort[i];
}

// ---------- GEMM1: g1 = dinv * (x @ W1) ----------
// block=256 threads / 128 rows; K-chunk 64 staged transposed in LDS (coalesced,
// 2-way-free banks); 2 threads per row split K 32/32; W via constexpr-base
// uniform address -> s_load + SGPR-operand FMA.
template<int KH>
__device__ __forceinline__ void gemm1_half(const float* __restrict__ xs,
                                           const float* __restrict__ W1,
                                           int kc, int lrow, float* __restrict__ acc) {
#pragma unroll 4
    for (int k = 0; k < 32; k++) {
        float xv = xs[(KH + k) * 129 + lrow];
        const float* w = W1 + (kc + KH + k) * H1;   // wave-uniform -> s_load
#pragma unroll
        for (int c = 0; c < H1; c++) acc[c] = fmaf(xv, w[c], acc[c]);
    }
}

__global__ __launch_bounds__(256) void k_gemm1(
    const float* __restrict__ x, const float* __restrict__ W1,
    const float* __restrict__ dinv, float* __restrict__ g1, int n) {
    __shared__ float xs[64 * 129];        // 33 KB; reused as reduce buffer
    const int t = threadIdx.x;
    const int rowbase = blockIdx.x * 128;
    const int lrow = t & 127;
    const int kh = t >> 7;                // wave-uniform (waves 0,1 -> 0; 2,3 -> 1)

    float acc[H1];
#pragma unroll
    for (int c = 0; c < H1; c++) acc[c] = 0.0f;

    for (int kc = 0; kc < F_IN; kc += 64) {
        __syncthreads();
        // stage 128 rows x 64 k: 2048 float4, 8 per thread, 16 lines/wave-instr
#pragma unroll
        for (int jj = 0; jj < 8; jj++) {
            int f = t + 256 * jj;
            int r = f >> 4;               // local row 0..127
            int kq = f & 15;              // float4 within 64-k chunk
            int grow = rowbase + r;
            float4 v = *(const float4*)(x + (size_t)min(grow, n - 1) * F_IN + kc + kq * 4);
            xs[(kq * 4 + 0) * 129 + r] = v.x;
            xs[(kq * 4 + 1) * 129 + r] = v.y;
            xs[(kq * 4 + 2) * 129 + r] = v.z;
            xs[(kq * 4 + 3) * 129 + r] = v.w;
        }
        __syncthreads();
        if (kh == 0) gemm1_half<0>(xs, W1, kc, lrow, acc);
        else         gemm1_half<32>(xs, W1, kc, lrow, acc);
    }
    __syncthreads();
    // combine the two K-halves via LDS (reuse xs), scale by dinv, store
    float* red = xs;                      // 128*16 floats
    if (kh == 1) {
#pragma unroll
        for (int c = 0; c < H1; c++) red[lrow * H1 + c] = acc[c];
    }
    __syncthreads();
    if (kh == 0) {
        int grow = rowbase + lrow;
        if (grow < n) {
            float d = dinv[grow];
#pragma unroll
            for (int c4 = 0; c4 < 4; c4++) {
                float4 o;
                o.x = (acc[c4 * 4 + 0] + red[lrow * H1 + c4 * 4 + 0]) * d;
                o.y = (acc[c4 * 4 + 1] + red[lrow * H1 + c4 * 4 + 1]) * d;
                o.z = (acc[c4 * 4 + 2] + red[lrow * H1 + c4 * 4 + 2]) * d;
                o.w = (acc[c4 * 4 + 3] + red[lrow * H1 + c4 * 4 + 3]) * d;
                *(float4*)(g1 + (size_t)grow * H1 + c4 * 4) = o;
            }
        }
    }
}

// ---------- aggregation 1: CSR pull, 16 lanes/node, fused ReLU ----------
__global__ __launch_bounds__(256) void k_agg1(
    const int* __restrict__ rowptr, const int* __restrict__ indeg,
    const int* __restrict__ csr_src, const float* __restrict__ g1,
    const float* __restrict__ dinv, const float* __restrict__ b1,
    float* __restrict__ r1, int n) {
    int t = threadIdx.x;
    int node = blockIdx.x * 16 + (t >> 4);
    int c = t & 15;
    if (node >= n) return;
    int start = rowptr[node];
    int end = start + indeg[node];
    float s0 = g1[(size_t)node * H1 + c];
    float s1 = 0.f, s2 = 0.f, s3 = 0.f, s4 = 0.f, s5 = 0.f, s6 = 0.f, s7 = 0.f;
    int i = start;
    for (; i + 8 <= end; i += 8) {
        int a0 = csr_src[i + 0], a1 = csr_src[i + 1], a2 = csr_src[i + 2], a3 = csr_src[i + 3];
        int a4 = csr_src[i + 4], a5 = csr_src[i + 5], a6 = csr_src[i + 6], a7 = csr_src[i + 7];
        s0 += g1[(size_t)a0 * H1 + c];
        s1 += g1[(size_t)a1 * H1 + c];
        s2 += g1[(size_t)a2 * H1 + c];
        s3 += g1[(size_t)a3 * H1 + c];
        s4 += g1[(size_t)a4 * H1 + c];
        s5 += g1[(size_t)a5 * H1 + c];
        s6 += g1[(size_t)a6 * H1 + c];
        s7 += g1[(size_t)a7 * H1 + c];
    }
    for (; i < end; i++) s0 += g1[(size_t)csr_src[i] * H1 + c];
    float sum = ((s0 + s1) + (s2 + s3)) + ((s4 + s5) + (s6 + s7));
    float val = fmaf(dinv[node], sum, b1[c]);
    r1[(size_t)node * H1 + c] = fmaxf(val, 0.f);
}

// ---------- GEMM2: g2 = dinv * (r1 @ W2), row stride 8, col 7 = 0 ----------
__global__ __launch_bounds__(256) void k_gemm2(
    const float* __restrict__ r1, const float* __restrict__ W2,
    const float* __restrict__ dinv, float* __restrict__ g2, int n) {
    __shared__ float xs[16 * 257];
    const int tid = threadIdx.x;
    const int rowbase = blockIdx.x * 256;
    const int row = rowbase + tid;

#pragma unroll
    for (int j = 0; j < 4; j++) {
        int flat = tid + 256 * j;
        int r = flat >> 2;
        int kq = flat & 3;
        int grow = rowbase + r;
        float4 v = make_float4(0.f, 0.f, 0.f, 0.f);
        if (grow < n) v = *(const float4*)(r1 + (size_t)grow * H1 + kq * 4);
        xs[(kq * 4 + 0) * 257 + r] = v.x;
        xs[(kq * 4 + 1) * 257 + r] = v.y;
        xs[(kq * 4 + 2) * 257 + r] = v.z;
        xs[(kq * 4 + 3) * 257 + r] = v.w;
    }
    __syncthreads();

    float acc[C_OUT];
#pragma unroll
    for (int c = 0; c < C_OUT; c++) acc[c] = 0.0f;
#pragma unroll
    for (int k = 0; k < H1; k++) {
        float xv = xs[k * 257 + tid];
        const float* w = W2 + k * C_OUT;
#pragma unroll
        for (int c = 0; c < C_OUT; c++) acc[c] = fmaf(xv, w[c], acc[c]);
    }

    if (row < n) {
        float d = dinv[row];
#pragma unroll
        for (int c = 0; c < C_OUT; c++) g2[(size_t)row * 8 + c] = acc[c] * d;
        g2[(size_t)row * 8 + 7] = 0.0f;
    }
}

// ---------- aggregation 2: CSR pull, 8 lanes/node + fused log_softmax ----------
__global__ __launch_bounds__(256) void k_agg2(
    const int* __restrict__ rowptr, const int* __restrict__ indeg,
    const int* __restrict__ csr_src, const float* __restrict__ g2,
    const float* __restrict__ dinv, const float* __restrict__ b2,
    float* __restrict__ out, int n) {
    int t = threadIdx.x;
    int node = blockIdx.x * 32 + (t >> 3);
    int c = t & 7;
    if (node >= n) return;
    int start = rowptr[node];
    int end = start + indeg[node];
    float s0 = (c < C_OUT) ? g2[(size_t)node * 8 + c] : 0.f;
    float s1 = 0.f, s2 = 0.f, s3 = 0.f, s4 = 0.f, s5 = 0.f, s6 = 0.f, s7 = 0.f;
    int i = start;
    for (; i + 8 <= end; i += 8) {
        int a0 = csr_src[i + 0], a1 = csr_src[i + 1], a2 = csr_src[i + 2], a3 = csr_src[i + 3];
        int a4 = csr_src[i + 4], a5 = csr_src[i + 5], a6 = csr_src[i + 6], a7 = csr_src[i + 7];
        s0 += g2[(size_t)a0 * 8 + c];
        s1 += g2[(size_t)a1 * 8 + c];
        s2 += g2[(size_t)a2 * 8 + c];
        s3 += g2[(size_t)a3 * 8 + c];
        s4 += g2[(size_t)a4 * 8 + c];
        s5 += g2[(size_t)a5 * 8 + c];
        s6 += g2[(size_t)a6 * 8 + c];
        s7 += g2[(size_t)a7 * 8 + c];
    }
    for (; i < end; i++) s0 += g2[(size_t)csr_src[i] * 8 + c];
    float sum = ((s0 + s1) + (s2 + s3)) + ((s4 + s5) + (s6 + s7));
    float bc = (c < C_OUT) ? b2[c] : 0.f;
    float val = fmaf(dinv[node], sum, bc);

    float vv = (c < C_OUT) ? val : -1e30f;
    float m = vv;
#pragma unroll
    for (int o = 1; o < 8; o <<= 1) m = fmaxf(m, __shfl_xor(m, o, 8));
    float ex = (c < C_OUT) ? expf(val - m) : 0.f;
    float se = ex;
#pragma unroll
    for (int o = 1; o < 8; o <<= 1) se += __shfl_xor(se, o, 8);
    float l = logf(se) + m;
    if (c < C_OUT) out[(size_t)node * C_OUT + c] = val - l;
}

extern "C" void kernel_launch(void* const* d_in, const int* in_sizes, int n_in,
                              void* d_out, int out_size, void* d_ws, size_t ws_size,
                              hipStream_t stream) {
    const float* x  = (const float*)d_in[0];
    const int* ei   = (const int*)d_in[1];
    const float* W1 = (const float*)d_in[2];
    const float* b1 = (const float*)d_in[3];
    const float* W2 = (const float*)d_in[4];
    const float* b2 = (const float*)d_in[5];
    float* out = (float*)d_out;

    const int n = in_sizes[0] / F_IN;     // 100000
    const int E = in_sizes[1] / 2;        // 3200000
    const int* src = ei;
    const int* dst = ei + E;

    const int B   = (n + BNODES - 1) >> BSHIFT;   // 782
    const int nfb = (E + 4095) >> 12;             // 782

    // workspace (4-byte units)
    int*   indeg    = (int*)d_ws;                          // n
    int*   rowptr   = indeg + n;                           // n
    float* dinv     = (float*)(rowptr + n);                // n
    int*   blocksum = (int*)(dinv + n);                    // 512
    int*   cnt      = blocksum + 512;                      // nfb*B
    int*   base     = cnt + (size_t)nfb * B;               // nfb*B
    float* g1       = (float*)(base + (size_t)nfb * B);    // 16n (g2 aliases low 8n)
    float* r1       = g1 + (size_t)16 * n;                 // 16n
    unsigned* bedge = (unsigned*)(r1 + (size_t)16 * n);    // E
    int*   csr_src  = (int*)(bedge + E);                   // E
    float* g2 = g1;

    const int nbN = (n + 255) / 256;   // 391
    const int nbE = (E + 255) / 256;   // 12500

    k_zero<<<nbN, 256, 0, stream>>>(indeg, n);
    k_hist<<<nbE, 256, 0, stream>>>(dst, indeg, E);
    k_dinv<<<nbN, 256, 0, stream>>>(indeg, dinv, n);
    k_scan1<<<nbN, 256, 0, stream>>>(indeg, rowptr, blocksum, n);
    k_scan2<<<1, 512, 0, stream>>>(blocksum, nbN);
    k_scan3<<<nbN, 256, 0, stream>>>(rowptr, blocksum, n);

    k_fill_p1<<<nfb, 1024, 0, stream>>>(dst, cnt, E, B);
    k_colscan<<<B, 256, 0, stream>>>(cnt, base, nfb, B);
    k_fill_p2<<<nfb, 1024, 0, stream>>>(src, dst, base, rowptr, bedge, E, B, n);
    k_fill_p3<<<B, 256, 0, stream>>>(rowptr, bedge, csr_src, n, E);

    k_gemm1<<<(n + 127) / 128, 256, 0, stream>>>(x, W1, dinv, g1, n);
    k_agg1<<<(n + 15) / 16, 256, 0, stream>>>(rowptr, indeg, csr_src, g1, dinv, b1, r1, n);
    k_gemm2<<<nbN, 256, 0, stream>>>(r1, W2, dinv, g2, n);
    k_agg2<<<(n + 31) / 32, 256, 0, stream>>>(rowptr, indeg, csr_src, g2, dinv, b2, out, n);
}

// Round 7
// 450.694 us; speedup vs baseline: 2.3125x; 1.2925x over previous
//
#include <hip/hip_runtime.h>
#include <math.h>

#define F_IN 512
#define H1 16
#define C_OUT 7
#define BSHIFT 7
#define BNODES 128
#define SRCMASK 0x1FFFFu
#define P3CAP 5120

// ---------- bucket fill pass 1: per-block bucket histogram ----------
__global__ __launch_bounds__(1024) void k_fill_p1(const int* __restrict__ dst,
                                                  int* __restrict__ cnt, int E, int B) {
    __shared__ int lh[1024];
    int t = threadIdx.x;
    for (int i = t; i < B; i += 1024) lh[i] = 0;
    __syncthreads();
    int e0 = blockIdx.x * 4096;
#pragma unroll
    for (int k = 0; k < 4; k++) {
        int e = e0 + t + 1024 * k;
        if (e < E) atomicAdd(&lh[dst[e] >> BSHIFT], 1);
    }
    __syncthreads();
    for (int i = t; i < B; i += 1024) cnt[(size_t)blockIdx.x * B + i] = lh[i];
}

// ---------- per-bucket exclusive scan over fill blocks (+ bucket totals) ----------
__global__ __launch_bounds__(256) void k_colscan(const int* __restrict__ cnt,
                                                 int* __restrict__ base,
                                                 int* __restrict__ btotal, int nfb, int B) {
    int b = blockIdx.x;
    int t = threadIdx.x;
    int loc[4];
    int s = 0;
    int j0 = t * 4;
#pragma unroll
    for (int k = 0; k < 4; k++) {
        int j = j0 + k;
        int v = (j < nfb) ? cnt[(size_t)j * B + b] : 0;
        loc[k] = s;
        s += v;
    }
    __shared__ int sh[256];
    sh[t] = s;
    __syncthreads();
    for (int off = 1; off < 256; off <<= 1) {
        int v2 = (t >= off) ? sh[t - off] : 0;
        __syncthreads();
        sh[t] += v2;
        __syncthreads();
    }
    int excl = sh[t] - s;
#pragma unroll
    for (int k = 0; k < 4; k++) {
        int j = j0 + k;
        if (j < nfb) base[(size_t)j * B + b] = excl + loc[k];
    }
    if (t == 255) btotal[b] = sh[255];
}

// ---------- exclusive scan of bucket totals -> bstart[0..B] (bstart[B]=E) ----------
__global__ __launch_bounds__(1024) void k_sscan(const int* __restrict__ btotal,
                                                int* __restrict__ bstart, int B, int E) {
    __shared__ int s[1024];
    int t = threadIdx.x;
    int v = (t < B) ? btotal[t] : 0;
    s[t] = v;
    __syncthreads();
    for (int off = 1; off < 1024; off <<= 1) {
        int x = (t >= off) ? s[t - off] : 0;
        __syncthreads();
        s[t] += x;
        __syncthreads();
    }
    if (t < B) bstart[t] = s[t] - v;
    if (t == 0) bstart[B] = E;
}

// ---------- bucket fill pass 2: LDS bucket-sort + run-coalesced writes ----------
__global__ __launch_bounds__(1024) void k_fill_p2(
    const int* __restrict__ src, const int* __restrict__ dst,
    const int* __restrict__ base, const int* __restrict__ bstart,
    unsigned* __restrict__ bedge, int E, int B) {
    __shared__ int lh[1024];
    __shared__ int scan[1024];
    __shared__ int gb[1024];
    __shared__ unsigned lsort[4096];
    __shared__ unsigned short lbk[4096];
    int t = threadIdx.x;
    for (int i = t; i < B; i += 1024) lh[i] = 0;
    __syncthreads();
    int e0 = blockIdx.x * 4096;
    int myb[4], myr[4];
    unsigned myv[4];
#pragma unroll
    for (int k = 0; k < 4; k++) {
        int e = e0 + t + 1024 * k;
        myb[k] = -1;
        if (e < E) {
            int d = dst[e];
            int b = d >> BSHIFT;
            myb[k] = b;
            myv[k] = ((unsigned)(d & (BNODES - 1)) << 17) | (unsigned)src[e];
            myr[k] = atomicAdd(&lh[b], 1);
        }
    }
    __syncthreads();
    int v = (t < B) ? lh[t] : 0;
    scan[t] = v;
    __syncthreads();
    for (int off = 1; off < 1024; off <<= 1) {
        int x = (t >= off) ? scan[t - off] : 0;
        __syncthreads();
        scan[t] += x;
        __syncthreads();
    }
    scan[t] -= v;
    __syncthreads();
    if (t < B) gb[t] = bstart[t] + base[(size_t)blockIdx.x * B + t];
    __syncthreads();
#pragma unroll
    for (int k = 0; k < 4; k++) {
        if (myb[k] >= 0) {
            int slot = scan[myb[k]] + myr[k];
            lsort[slot] = myv[k];
            lbk[slot] = (unsigned short)myb[k];
        }
    }
    __syncthreads();
    int elim = min(4096, E - e0);
    for (int i = t; i < elim; i += 1024) {
        int b = lbk[i];
        bedge[gb[b] + (i - scan[b])] = lsort[i];
    }
}

// ---------- fill pass 3: per-bucket counting sort by node -> csr_src,
//            and emit indeg / rowptr / dinv (no global atomics anywhere) ----------
__global__ __launch_bounds__(256) void k_fill_p3(
    const int* __restrict__ bstart, const unsigned* __restrict__ bedge,
    int* __restrict__ csr_src, int* __restrict__ indeg, int* __restrict__ rowptr,
    float* __restrict__ dinv, int n) {
    __shared__ int lh[BNODES];     // per-node counts
    __shared__ int off[BNODES];    // exclusive scan of lh
    __shared__ int lc[BNODES];     // placement cursors
    __shared__ int sc[BNODES];
    __shared__ int lsort[P3CAP];
    int t = threadIdx.x;
    int bb = blockIdx.x;
    int nodebase = bb << BSHIFT;
    int gs = bstart[bb];
    int ge = bstart[bb + 1];
    for (int i = t; i < BNODES; i += 256) { lh[i] = 0; lc[i] = 0; }
    __syncthreads();
    // phase 1: count
    for (int e = gs + t; e < ge; e += 256) {
        unsigned v = bedge[e];
        atomicAdd(&lh[v >> 17], 1);
    }
    __syncthreads();
    // 128-wide exclusive scan of lh -> off
    int sv = (t < BNODES) ? lh[t] : 0;
    if (t < BNODES) sc[t] = sv;
    __syncthreads();
    for (int o = 1; o < BNODES; o <<= 1) {
        int x = (t < BNODES && t >= o) ? sc[t - o] : 0;
        __syncthreads();
        if (t < BNODES) sc[t] += x;
        __syncthreads();
    }
    if (t < BNODES) off[t] = sc[t] - sv;
    __syncthreads();
    // emit per-node metadata (coalesced)
    if (t < BNODES) {
        int node = nodebase + t;
        if (node < n) {
            indeg[node] = sv;
            rowptr[node] = gs + off[t];
            dinv[node] = rsqrtf(1.0f + (float)sv);
        }
    }
    // phase 2: place
    for (int e = gs + t; e < ge; e += 256) {
        unsigned v = bedge[e];
        int dl = (int)(v >> 17);
        int rank = atomicAdd(&lc[dl], 1);
        int pos = off[dl] + rank;
        int svv = (int)(v & SRCMASK);
        if (pos < P3CAP) lsort[pos] = svv;
        else csr_src[gs + pos] = svv;       // overflow fallback (statistically never)
    }
    __syncthreads();
    int lim = min(ge - gs, P3CAP);
    for (int i = t; i < lim; i += 256) csr_src[gs + i] = lsort[i];
}

// ---------- GEMM1: g1 = dinv * (x @ W1) ----------
template<int KH>
__device__ __forceinline__ void gemm1_half(const float* __restrict__ xs,
                                           const float* __restrict__ W1,
                                           int kc, int lrow, float* __restrict__ acc) {
#pragma unroll 4
    for (int k = 0; k < 32; k++) {
        float xv = xs[(KH + k) * 129 + lrow];
        const float* w = W1 + (kc + KH + k) * H1;   // wave-uniform -> s_load
#pragma unroll
        for (int c = 0; c < H1; c++) acc[c] = fmaf(xv, w[c], acc[c]);
    }
}

__global__ __launch_bounds__(256) void k_gemm1(
    const float* __restrict__ x, const float* __restrict__ W1,
    const float* __restrict__ dinv, float* __restrict__ g1, int n) {
    __shared__ float xs[64 * 129];
    const int t = threadIdx.x;
    const int rowbase = blockIdx.x * 128;
    const int lrow = t & 127;
    const int kh = t >> 7;

    float acc[H1];
#pragma unroll
    for (int c = 0; c < H1; c++) acc[c] = 0.0f;

    for (int kc = 0; kc < F_IN; kc += 64) {
        __syncthreads();
#pragma unroll
        for (int jj = 0; jj < 8; jj++) {
            int f = t + 256 * jj;
            int r = f >> 4;
            int kq = f & 15;
            int grow = rowbase + r;
            float4 v = *(const float4*)(x + (size_t)min(grow, n - 1) * F_IN + kc + kq * 4);
            xs[(kq * 4 + 0) * 129 + r] = v.x;
            xs[(kq * 4 + 1) * 129 + r] = v.y;
            xs[(kq * 4 + 2) * 129 + r] = v.z;
            xs[(kq * 4 + 3) * 129 + r] = v.w;
        }
        __syncthreads();
        if (kh == 0) gemm1_half<0>(xs, W1, kc, lrow, acc);
        else         gemm1_half<32>(xs, W1, kc, lrow, acc);
    }
    __syncthreads();
    float* red = xs;
    if (kh == 1) {
#pragma unroll
        for (int c = 0; c < H1; c++) red[lrow * H1 + c] = acc[c];
    }
    __syncthreads();
    if (kh == 0) {
        int grow = rowbase + lrow;
        if (grow < n) {
            float d = dinv[grow];
#pragma unroll
            for (int c4 = 0; c4 < 4; c4++) {
                float4 o;
                o.x = (acc[c4 * 4 + 0] + red[lrow * H1 + c4 * 4 + 0]) * d;
                o.y = (acc[c4 * 4 + 1] + red[lrow * H1 + c4 * 4 + 1]) * d;
                o.z = (acc[c4 * 4 + 2] + red[lrow * H1 + c4 * 4 + 2]) * d;
                o.w = (acc[c4 * 4 + 3] + red[lrow * H1 + c4 * 4 + 3]) * d;
                *(float4*)(g1 + (size_t)grow * H1 + c4 * 4) = o;
            }
        }
    }
}

// ---------- aggregation 1: CSR pull, 16 lanes/node, fused ReLU ----------
__global__ __launch_bounds__(256) void k_agg1(
    const int* __restrict__ rowptr, const int* __restrict__ indeg,
    const int* __restrict__ csr_src, const float* __restrict__ g1,
    const float* __restrict__ dinv, const float* __restrict__ b1,
    float* __restrict__ r1, int n) {
    int t = threadIdx.x;
    int node = blockIdx.x * 16 + (t >> 4);
    int c = t & 15;
    if (node >= n) return;
    int start = rowptr[node];
    int end = start + indeg[node];
    float s0 = g1[(size_t)node * H1 + c];
    float s1 = 0.f, s2 = 0.f, s3 = 0.f, s4 = 0.f, s5 = 0.f, s6 = 0.f, s7 = 0.f;
    int i = start;
    for (; i + 8 <= end; i += 8) {
        int a0 = csr_src[i + 0], a1 = csr_src[i + 1], a2 = csr_src[i + 2], a3 = csr_src[i + 3];
        int a4 = csr_src[i + 4], a5 = csr_src[i + 5], a6 = csr_src[i + 6], a7 = csr_src[i + 7];
        s0 += g1[(size_t)a0 * H1 + c];
        s1 += g1[(size_t)a1 * H1 + c];
        s2 += g1[(size_t)a2 * H1 + c];
        s3 += g1[(size_t)a3 * H1 + c];
        s4 += g1[(size_t)a4 * H1 + c];
        s5 += g1[(size_t)a5 * H1 + c];
        s6 += g1[(size_t)a6 * H1 + c];
        s7 += g1[(size_t)a7 * H1 + c];
    }
    for (; i < end; i++) s0 += g1[(size_t)csr_src[i] * H1 + c];
    float sum = ((s0 + s1) + (s2 + s3)) + ((s4 + s5) + (s6 + s7));
    float val = fmaf(dinv[node], sum, b1[c]);
    r1[(size_t)node * H1 + c] = fmaxf(val, 0.f);
}

// ---------- GEMM2: g2 = dinv * (r1 @ W2), row stride 8, col 7 = 0 ----------
__global__ __launch_bounds__(256) void k_gemm2(
    const float* __restrict__ r1, const float* __restrict__ W2,
    const float* __restrict__ dinv, float* __restrict__ g2, int n) {
    __shared__ float xs[16 * 257];
    const int tid = threadIdx.x;
    const int rowbase = blockIdx.x * 256;
    const int row = rowbase + tid;

#pragma unroll
    for (int j = 0; j < 4; j++) {
        int flat = tid + 256 * j;
        int r = flat >> 2;
        int kq = flat & 3;
        int grow = rowbase + r;
        float4 v = make_float4(0.f, 0.f, 0.f, 0.f);
        if (grow < n) v = *(const float4*)(r1 + (size_t)grow * H1 + kq * 4);
        xs[(kq * 4 + 0) * 257 + r] = v.x;
        xs[(kq * 4 + 1) * 257 + r] = v.y;
        xs[(kq * 4 + 2) * 257 + r] = v.z;
        xs[(kq * 4 + 3) * 257 + r] = v.w;
    }
    __syncthreads();

    float acc[C_OUT];
#pragma unroll
    for (int c = 0; c < C_OUT; c++) acc[c] = 0.0f;
#pragma unroll
    for (int k = 0; k < H1; k++) {
        float xv = xs[k * 257 + tid];
        const float* w = W2 + k * C_OUT;
#pragma unroll
        for (int c = 0; c < C_OUT; c++) acc[c] = fmaf(xv, w[c], acc[c]);
    }

    if (row < n) {
        float d = dinv[row];
#pragma unroll
        for (int c = 0; c < C_OUT; c++) g2[(size_t)row * 8 + c] = acc[c] * d;
        g2[(size_t)row * 8 + 7] = 0.0f;
    }
}

// ---------- aggregation 2: CSR pull, 8 lanes/node + fused log_softmax ----------
__global__ __launch_bounds__(256) void k_agg2(
    const int* __restrict__ rowptr, const int* __restrict__ indeg,
    const int* __restrict__ csr_src, const float* __restrict__ g2,
    const float* __restrict__ dinv, const float* __restrict__ b2,
    float* __restrict__ out, int n) {
    int t = threadIdx.x;
    int node = blockIdx.x * 32 + (t >> 3);
    int c = t & 7;
    if (node >= n) return;
    int start = rowptr[node];
    int end = start + indeg[node];
    float s0 = (c < C_OUT) ? g2[(size_t)node * 8 + c] : 0.f;
    float s1 = 0.f, s2 = 0.f, s3 = 0.f, s4 = 0.f, s5 = 0.f, s6 = 0.f, s7 = 0.f;
    int i = start;
    for (; i + 8 <= end; i += 8) {
        int a0 = csr_src[i + 0], a1 = csr_src[i + 1], a2 = csr_src[i + 2], a3 = csr_src[i + 3];
        int a4 = csr_src[i + 4], a5 = csr_src[i + 5], a6 = csr_src[i + 6], a7 = csr_src[i + 7];
        s0 += g2[(size_t)a0 * 8 + c];
        s1 += g2[(size_t)a1 * 8 + c];
        s2 += g2[(size_t)a2 * 8 + c];
        s3 += g2[(size_t)a3 * 8 + c];
        s4 += g2[(size_t)a4 * 8 + c];
        s5 += g2[(size_t)a5 * 8 + c];
        s6 += g2[(size_t)a6 * 8 + c];
        s7 += g2[(size_t)a7 * 8 + c];
    }
    for (; i < end; i++) s0 += g2[(size_t)csr_src[i] * 8 + c];
    float sum = ((s0 + s1) + (s2 + s3)) + ((s4 + s5) + (s6 + s7));
    float bc = (c < C_OUT) ? b2[c] : 0.f;
    float val = fmaf(dinv[node], sum, bc);

    float vv = (c < C_OUT) ? val : -1e30f;
    float m = vv;
#pragma unroll
    for (int o = 1; o < 8; o <<= 1) m = fmaxf(m, __shfl_xor(m, o, 8));
    float ex = (c < C_OUT) ? expf(val - m) : 0.f;
    float se = ex;
#pragma unroll
    for (int o = 1; o < 8; o <<= 1) se += __shfl_xor(se, o, 8);
    float l = logf(se) + m;
    if (c < C_OUT) out[(size_t)node * C_OUT + c] = val - l;
}

extern "C" void kernel_launch(void* const* d_in, const int* in_sizes, int n_in,
                              void* d_out, int out_size, void* d_ws, size_t ws_size,
                              hipStream_t stream) {
    const float* x  = (const float*)d_in[0];
    const int* ei   = (const int*)d_in[1];
    const float* W1 = (const float*)d_in[2];
    const float* b1 = (const float*)d_in[3];
    const float* W2 = (const float*)d_in[4];
    const float* b2 = (const float*)d_in[5];
    float* out = (float*)d_out;

    const int n = in_sizes[0] / F_IN;     // 100000
    const int E = in_sizes[1] / 2;        // 3200000
    const int* src = ei;
    const int* dst = ei + E;

    const int B   = (n + BNODES - 1) >> BSHIFT;   // 782
    const int nfb = (E + 4095) >> 12;             // 782

    // workspace (4-byte units)
    int*   indeg    = (int*)d_ws;                          // n
    int*   rowptr   = indeg + n;                           // n
    float* dinv     = (float*)(rowptr + n);                // n
    int*   btotal   = (int*)(dinv + n);                    // B
    int*   bstart   = btotal + B;                          // B+1
    int*   cnt      = bstart + B + 1;                      // nfb*B
    int*   base     = cnt + (size_t)nfb * B;               // nfb*B
    float* g1       = (float*)(base + (size_t)nfb * B);    // 16n (g2 aliases low 8n)
    float* r1       = g1 + (size_t)16 * n;                 // 16n
    unsigned* bedge = (unsigned*)(r1 + (size_t)16 * n);    // E
    int*   csr_src  = (int*)(bedge + E);                   // E
    float* g2 = g1;

    const int nbN = (n + 255) / 256;   // 391

    k_fill_p1<<<nfb, 1024, 0, stream>>>(dst, cnt, E, B);
    k_colscan<<<B, 256, 0, stream>>>(cnt, base, btotal, nfb, B);
    k_sscan<<<1, 1024, 0, stream>>>(btotal, bstart, B, E);
    k_fill_p2<<<nfb, 1024, 0, stream>>>(src, dst, base, bstart, bedge, E, B);
    k_fill_p3<<<B, 256, 0, stream>>>(bstart, bedge, csr_src, indeg, rowptr, dinv, n);

    k_gemm1<<<(n + 127) / 128, 256, 0, stream>>>(x, W1, dinv, g1, n);
    k_agg1<<<(n + 15) / 16, 256, 0, stream>>>(rowptr, indeg, csr_src, g1, dinv, b1, r1, n);
    k_gemm2<<<nbN, 256, 0, stream>>>(r1, W2, dinv, g2, n);
    k_agg2<<<(n + 31) / 32, 256, 0, stream>>>(rowptr, indeg, csr_src, g2, dinv, b2, out, n);
}